// Round 10
// baseline (357.434 us; speedup 1.0000x reference)
//
#include <hip/hip_runtime.h>
#include <math.h>

#define NN 20000
#define EE 256000
#define GG 64
#define CDIV(a,b) (((a)+(b)-1)/(b))
#define RB4 157   // CDIV(NN,128) row-blocks in layer-4 GEMM

typedef __attribute__((ext_vector_type(8))) short bf16x8;
typedef __attribute__((ext_vector_type(4))) float f32x4;

__device__ __forceinline__ unsigned fkey(float f) {
  unsigned u = __float_as_uint(f);
  return (u & 0x80000000u) ? ~u : (u | 0x80000000u);
}
__device__ __forceinline__ float fdec(unsigned k) {
  unsigned u = (k & 0x80000000u) ? (k ^ 0x80000000u) : ~k;
  return __uint_as_float(u);
}
__device__ __forceinline__ unsigned short rne_bf16(float f) {
  unsigned u = __float_as_uint(f);
  unsigned r = (u + 0x7fffu + ((u >> 16) & 1u)) >> 16;
  return (unsigned short)r;
}

// ---------------- graph preprocessing ----------------

__global__ void k_prep(int* deg) {
  int i = blockIdx.x*blockDim.x + threadIdx.x;
  if (i < NN) deg[i] = 1;   // self-loop
}

__global__ void k_deg(const int* __restrict__ dst, int* deg) {
  int i = blockIdx.x*blockDim.x + threadIdx.x;
  if (i < EE) atomicAdd(&deg[dst[i]], 1);
}

__global__ __launch_bounds__(256) void k_scan_bsum(const int* __restrict__ deg,
                                                   int* __restrict__ bsum) {
  __shared__ int red[256];
  int b = blockIdx.x, t = threadIdx.x;
  int idx = b*1024 + t*4;
  int4 v = make_int4(0,0,0,0);
  if (idx < NN) v = *(const int4*)&deg[idx];
  red[t] = v.x + v.y + v.z + v.w;
  __syncthreads();
  for (int off = 128; off > 0; off >>= 1) {
    if (t < off) red[t] += red[t+off];
    __syncthreads();
  }
  if (t == 0) bsum[b] = red[0];
}

__global__ __launch_bounds__(256) void k_scan_apply(
    const int* __restrict__ deg, const int* __restrict__ bsum,
    int* __restrict__ offsets, int* __restrict__ cursor, float* __restrict__ dinv) {
  __shared__ int base_s;
  __shared__ int tsum[256];
  int b = blockIdx.x, t = threadIdx.x;
  if (t == 0) {
    int s = 0;
    for (int i = 0; i < b; ++i) s += bsum[i];
    base_s = s;
  }
  int idx = b*1024 + t*4;
  int4 v = make_int4(0,0,0,0);
  if (idx < NN) v = *(const int4*)&deg[idx];
  tsum[t] = v.x + v.y + v.z + v.w;
  __syncthreads();
  for (int off = 1; off < 256; off <<= 1) {
    int u = (t >= off) ? tsum[t-off] : 0;
    __syncthreads();
    tsum[t] += u;
    __syncthreads();
  }
  int excl = (t == 0) ? 0 : tsum[t-1];
  if (idx < NN) {
    int base = base_s + excl;
    int o0 = base;
    int o1 = o0 + v.x;
    int o2 = o1 + v.y;
    int o3 = o2 + v.z;
    *(int4*)&offsets[idx] = make_int4(o0,o1,o2,o3);
    *(int4*)&cursor[idx]  = make_int4(o0,o1,o2,o3);
    float4 dv;
    dv.x = rsqrtf((float)v.x); dv.y = rsqrtf((float)v.y);
    dv.z = rsqrtf((float)v.z); dv.w = rsqrtf((float)v.w);
    *(float4*)&dinv[idx] = dv;
    if (idx + 4 == NN) offsets[NN] = o3 + v.w;
  }
}

__global__ void k_fill(const int* __restrict__ srcv, const int* __restrict__ dstv,
                       const float* __restrict__ dinv, int* cursor,
                       int* __restrict__ csr_src, float* __restrict__ csr_w) {
  int i = blockIdx.x*blockDim.x + threadIdx.x;
  if (i < EE) {
    int s = srcv[i], d = dstv[i];
    int pos = atomicAdd(&cursor[d], 1);
    csr_src[pos] = s;
    csr_w[pos] = dinv[s] * dinv[d];
  } else if (i < EE + NN) {
    int n = i - EE;
    int pos = atomicAdd(&cursor[n], 1);
    csr_src[pos] = n;
    float di = dinv[n];
    csr_w[pos] = di * di;
  }
}

// ---------------- aggregation ----------------

template<int C, int TX, int TY>
__global__ void k_agg(const float* __restrict__ in, const int* __restrict__ offsets,
                      const int* __restrict__ csr_src, const float* __restrict__ csr_w,
                      float* __restrict__ out) {
  int node = blockIdx.x * TY + threadIdx.y;
  if (node >= NN) return;
  int x = threadIdx.x;
  int k0 = offsets[node], k1 = offsets[node+1];
  if (x < C) {
    float acc = 0.f;
    for (int k = k0; k < k1; ++k) {
      int s = csr_src[k];
      float w = csr_w[k];
      acc += w * in[s*C + x];
    }
    out[node*C + x] = acc;
  }
}

template<int C, int TY>
__global__ void k_agg_f4(const float* __restrict__ in, const float* __restrict__ st,
                         const float* __restrict__ g, const float* __restrict__ be,
                         const int* __restrict__ offsets, const int* __restrict__ csr_src,
                         const float* __restrict__ csr_w, float* __restrict__ out) {
  int node = blockIdx.x*TY + threadIdx.y;
  if (node >= NN) return;
  int c0 = threadIdx.x*4;
  float4 mean = *(const float4*)&st[c0];
  float4 rstd = *(const float4*)&st[C+c0];
  float4 gv = *(const float4*)&g[c0];
  float4 bv = *(const float4*)&be[c0];
  float sx = gv.x*rstd.x, hx = bv.x - mean.x*sx;
  float sy = gv.y*rstd.y, hy = bv.y - mean.y*sy;
  float sz = gv.z*rstd.z, hz = bv.z - mean.z*sz;
  float sw = gv.w*rstd.w, hw = bv.w - mean.w*sw;
  int k0 = offsets[node], k1 = offsets[node+1];
  float a0=0.f,a1=0.f,a2=0.f,a3=0.f;
  for (int k = k0; k < k1; ++k) {
    int s = csr_src[k]; float w = csr_w[k];
    float4 v = *(const float4*)&in[s*C + c0];
    a0 += w*fmaxf(v.x*sx+hx, 0.f);
    a1 += w*fmaxf(v.y*sy+hy, 0.f);
    a2 += w*fmaxf(v.z*sz+hz, 0.f);
    a3 += w*fmaxf(v.w*sw+hw, 0.f);
  }
  *(float4*)&out[node*C+c0] = make_float4(a0,a1,a2,a3);
}

__global__ void k_agg_bf_f4(const float* __restrict__ in, const float* __restrict__ st,
                            const float* __restrict__ g, const float* __restrict__ be,
                            const int* __restrict__ offsets, const int* __restrict__ csr_src,
                            const float* __restrict__ csr_w, unsigned short* __restrict__ out) {
  int node = blockIdx.x*8 + threadIdx.y;   // block (32,8)
  if (node >= NN) return;
  int c0 = threadIdx.x*4;
  float4 mean = *(const float4*)&st[c0];
  float4 rstd = *(const float4*)&st[128+c0];
  float4 gv = *(const float4*)&g[c0];
  float4 bv = *(const float4*)&be[c0];
  float sx = gv.x*rstd.x, hx = bv.x - mean.x*sx;
  float sy = gv.y*rstd.y, hy = bv.y - mean.y*sy;
  float sz = gv.z*rstd.z, hz = bv.z - mean.z*sz;
  float sw = gv.w*rstd.w, hw = bv.w - mean.w*sw;
  int k0 = offsets[node], k1 = offsets[node+1];
  float a0=0.f,a1=0.f,a2=0.f,a3=0.f;
  for (int k = k0; k < k1; ++k) {
    int s = csr_src[k]; float w = csr_w[k];
    float4 v = *(const float4*)&in[s*128 + c0];
    a0 += w*fmaxf(v.x*sx+hx, 0.f);
    a1 += w*fmaxf(v.y*sy+hy, 0.f);
    a2 += w*fmaxf(v.z*sz+hz, 0.f);
    a3 += w*fmaxf(v.w*sw+hw, 0.f);
  }
  ushort4 o;
  o.x = rne_bf16(a0); o.y = rne_bf16(a1); o.z = rne_bf16(a2); o.w = rne_bf16(a3);
  *(ushort4*)&out[node*128 + c0] = o;
}

// W4 [128,1024] fp32 -> Wt [1024,128] bf16
__global__ void k_wprep(const float* __restrict__ W, unsigned short* __restrict__ out) {
  int i = blockIdx.x*256 + threadIdx.x;
  if (i >= 128*1024) return;
  int k = i >> 10, c = i & 1023;
  out[c*128 + k] = rne_bf16(W[i]);
}

// ---------------- small GEMM (layers 1-3), no bias, fused stats ----------------

template<int K, int OUT, int ROWS>
__global__ __launch_bounds__(256) void k_gemm_small(
    const float* __restrict__ A, const float* __restrict__ W,
    float* __restrict__ out, float* __restrict__ pstats) {
  constexpr int RG  = 256 / OUT;
  constexpr int RPT = ROWS / RG;
  __shared__ float Ws[K*OUT];
  __shared__ float As[ROWS*K];
  __shared__ float reds[2][RG][OUT];
  int t = threadIdx.x;
  for (int i = t; i < K*OUT; i += 256) Ws[i] = W[i];
  int row0 = blockIdx.x * ROWS;
  for (int i = t; i < ROWS*K; i += 256) As[i] = A[row0*K + i];
  __syncthreads();
  int j  = t % OUT;
  int rg = t / OUT;
  float acc[RPT] = {};
  for (int k = 0; k < K; ++k) {
    float w = Ws[k*OUT + j];
    #pragma unroll
    for (int i = 0; i < RPT; ++i)
      acc[i] += As[(rg*RPT + i)*K + k] * w;
  }
  float s = 0.f, ss = 0.f;
  #pragma unroll
  for (int i = 0; i < RPT; ++i) {
    out[(row0 + rg*RPT + i)*OUT + j] = acc[i];
    s += acc[i]; ss += acc[i]*acc[i];
  }
  reds[0][rg][j] = s; reds[1][rg][j] = ss;
  __syncthreads();
  if (rg == 0) {
    float S = 0.f, SS = 0.f;
    #pragma unroll
    for (int r = 0; r < RG; ++r) { S += reds[0][r][j]; SS += reds[1][r][j]; }
    int p = blockIdx.x & 15;
    atomicAdd(&pstats[p*2*OUT + j], S);
    atomicAdd(&pstats[p*2*OUT + OUT + j], SS);
  }
}

template<int C>
__global__ void k_finalize_ps(const float* __restrict__ pstats, float* __restrict__ stats) {
  int c = blockIdx.x*64 + threadIdx.x;
  if (c >= C) return;
  float s = 0.f, ss = 0.f;
  #pragma unroll
  for (int p = 0; p < 16; ++p) { s += pstats[p*2*C + c]; ss += pstats[p*2*C + C + c]; }
  float m = s * (1.f/NN);
  float v = ss * (1.f/NN) - m*m;
  stats[c] = m;
  stats[C+c] = rsqrtf(v + 1e-5f);
}

// ---------------- layer-4: bf16 MFMA GEMM, contention-free stats, reduced pool atomics ----------------

__global__ __launch_bounds__(256) void k_gemm_l4_mfma(
    const unsigned short* __restrict__ A, const unsigned short* __restrict__ Bt,
    const int* __restrict__ batch,
    float* __restrict__ ps4, unsigned* __restrict__ pmax, unsigned* __restrict__ pmin) {
  __shared__ unsigned short As[128*128];
  __shared__ unsigned short Bs[128*128];
  int t = threadIdx.x;
  int row0 = blockIdx.x * 128;
  int col0 = blockIdx.y * 128;
  #pragma unroll
  for (int j = 0; j < 8; ++j) {
    int c = j*256 + t;
    int r = c >> 4, ck = c & 15;
    int rg = row0 + r;
    ulonglong2 v; v.x = 0; v.y = 0;
    if (rg < NN) v = *(const ulonglong2*)&A[rg*128 + ck*8];
    *(ulonglong2*)&As[r*128 + (ck ^ (r & 7))*8] = v;
  }
  #pragma unroll
  for (int j = 0; j < 8; ++j) {
    int c = j*256 + t;
    int r = c >> 4, ck = c & 15;
    ulonglong2 v = *(const ulonglong2*)&Bt[(col0 + r)*128 + ck*8];
    *(ulonglong2*)&Bs[r*128 + (ck ^ (r & 7))*8] = v;
  }
  __syncthreads();

  int w = t >> 6, l = t & 63;
  int wr = w >> 1, wc = w & 1;
  int lrow = l & 15, lk = l >> 4;
  f32x4 acc[4][4] = {};
  #pragma unroll
  for (int ks = 0; ks < 4; ++ks) {
    int kc = ks*4 + lk;
    bf16x8 a[4], b[4];
    #pragma unroll
    for (int m = 0; m < 4; ++m) {
      int r = wr*64 + m*16 + lrow;
      a[m] = *(const bf16x8*)&As[r*128 + (kc ^ (r & 7))*8];
    }
    #pragma unroll
    for (int n = 0; n < 4; ++n) {
      int r = wc*64 + n*16 + lrow;
      b[n] = *(const bf16x8*)&Bs[r*128 + (kc ^ (r & 7))*8];
    }
    #pragma unroll
    for (int m = 0; m < 4; ++m)
      #pragma unroll
      for (int n = 0; n < 4; ++n)
        acc[m][n] = __builtin_amdgcn_mfma_f32_16x16x32_bf16(a[m], b[n], acc[m][n], 0, 0, 0);
  }

  // ---- epilogue ----
  int rbase = row0 + wr*64;
  float s[4] = {}, ss[4] = {};
  float mx[4], mn[4];
  #pragma unroll
  for (int n = 0; n < 4; ++n) { mx[n] = -3.4e38f; mn[n] = 3.4e38f; }
  #pragma unroll
  for (int m = 0; m < 4; ++m)
    #pragma unroll
    for (int r = 0; r < 4; ++r) {
      int row_g = rbase + m*16 + lk*4 + r;
      if (row_g < NN) {
        #pragma unroll
        for (int n = 0; n < 4; ++n) {
          float v = acc[m][n][r];
          s[n] += v; ss[n] += v*v;
          mx[n] = fmaxf(mx[n], v); mn[n] = fminf(mn[n], v);
        }
      }
    }
  // wave-level column totals: lanes l, l^16, l^32, l^48 share a column
  #pragma unroll
  for (int n = 0; n < 4; ++n) {
    s[n]  += __shfl_xor(s[n], 16);  s[n]  += __shfl_xor(s[n], 32);
    ss[n] += __shfl_xor(ss[n], 16); ss[n] += __shfl_xor(ss[n], 32);
  }

  // block-level pool span
  int rlast_b = min(row0 + 127, NN - 1);
  int glo_b = batch[row0], ghi_b = batch[rlast_b];
  bool block_same = (glo_b == ghi_b);
  if (block_same) {
    #pragma unroll
    for (int n = 0; n < 4; ++n) {
      mx[n] = fmaxf(mx[n], __shfl_xor(mx[n], 16)); mx[n] = fmaxf(mx[n], __shfl_xor(mx[n], 32));
      mn[n] = fminf(mn[n], __shfl_xor(mn[n], 16)); mn[n] = fminf(mn[n], __shfl_xor(mn[n], 32));
    }
  }

  __syncthreads();  // done with As/Bs as bf16 tiles — reuse as scratch
  float* scr_s = (float*)As;   // [2wr][2wc][4n][16] x2 (s,ss) = 1KB
  float* scr_p = (float*)Bs;   // [2wr][2wc][4n][16] x2 (mx,mn)
  if (l < 16) {
    #pragma unroll
    for (int n = 0; n < 4; ++n) {
      int si = (((wr*2 + wc)*4 + n)*16 + l)*2;
      scr_s[si]   = s[n];
      scr_s[si+1] = ss[n];
      if (block_same) { scr_p[si] = mx[n]; scr_p[si+1] = mn[n]; }
    }
  }
  __syncthreads();
  if (wr == 0 && l < 16) {
    #pragma unroll
    for (int n = 0; n < 4; ++n) {
      int si0 = (((0*2 + wc)*4 + n)*16 + l)*2;
      int si1 = (((1*2 + wc)*4 + n)*16 + l)*2;
      int cg  = col0 + wc*64 + n*16 + l;     // global column
      // stats partial: contiguous, no atomics
      ps4[(size_t)blockIdx.x*2048 + cg]        = scr_s[si0]   + scr_s[si1];
      ps4[(size_t)blockIdx.x*2048 + 1024 + cg] = scr_s[si0+1] + scr_s[si1+1];
      if (block_same) {
        float bmx = fmaxf(scr_p[si0],   scr_p[si1]);
        float bmn = fminf(scr_p[si0+1], scr_p[si1+1]);
        if (bmx > -3.0e38f) atomicMax(&pmax[glo_b*1024 + cg], fkey(bmx));
        if (bmn <  3.0e38f) atomicMin(&pmin[glo_b*1024 + cg], fkey(bmn));
      }
    }
  }
  if (!block_same && rbase < NN) {
    // per-wave pool (graph boundary in block)
    int rlast = min(rbase + 63, NN - 1);
    int glo = batch[rbase], ghi = batch[rlast];
    if (glo == ghi) {
      #pragma unroll
      for (int n = 0; n < 4; ++n) {
        mx[n] = fmaxf(mx[n], __shfl_xor(mx[n], 16)); mx[n] = fmaxf(mx[n], __shfl_xor(mx[n], 32));
        mn[n] = fminf(mn[n], __shfl_xor(mn[n], 16)); mn[n] = fminf(mn[n], __shfl_xor(mn[n], 32));
      }
      if (l < 16) {
        #pragma unroll
        for (int n = 0; n < 4; ++n) {
          int cg = col0 + wc*64 + n*16 + l;
          atomicMax(&pmax[glo*1024 + cg], fkey(mx[n]));
          atomicMin(&pmin[glo*1024 + cg], fkey(mn[n]));
        }
      }
    } else {
      int gb[4][4];
      #pragma unroll
      for (int m = 0; m < 4; ++m)
        #pragma unroll
        for (int r = 0; r < 4; ++r) {
          int row_g = rbase + m*16 + lk*4 + r;
          gb[m][r] = (row_g < NN) ? batch[row_g] : -1;
        }
      for (int g = glo; g <= ghi; ++g) {
        float gmx[4], gmn[4];
        #pragma unroll
        for (int n = 0; n < 4; ++n) { gmx[n] = -3.4e38f; gmn[n] = 3.4e38f; }
        #pragma unroll
        for (int m = 0; m < 4; ++m)
          #pragma unroll
          for (int r = 0; r < 4; ++r) {
            bool in_g = (gb[m][r] == g);
            #pragma unroll
            for (int n = 0; n < 4; ++n) {
              float v = acc[m][n][r];
              gmx[n] = in_g ? fmaxf(gmx[n], v) : gmx[n];
              gmn[n] = in_g ? fminf(gmn[n], v) : gmn[n];
            }
          }
        #pragma unroll
        for (int n = 0; n < 4; ++n) {
          gmx[n] = fmaxf(gmx[n], __shfl_xor(gmx[n], 16)); gmx[n] = fmaxf(gmx[n], __shfl_xor(gmx[n], 32));
          gmn[n] = fminf(gmn[n], __shfl_xor(gmn[n], 16)); gmn[n] = fminf(gmn[n], __shfl_xor(gmn[n], 32));
        }
        if (l < 16) {
          #pragma unroll
          for (int n = 0; n < 4; ++n) {
            int cg = col0 + wc*64 + n*16 + l;
            if (gmx[n] > -3.0e38f) atomicMax(&pmax[g*1024 + cg], fkey(gmx[n]));
            if (gmn[n] <  3.0e38f) atomicMin(&pmin[g*1024 + cg], fkey(gmn[n]));
          }
        }
      }
    }
  }
}

// reduce ps4 [RB4][2][1024] -> stats4 [2][1024]
__global__ void k_finalize_l4(const float* __restrict__ ps4, float* __restrict__ stats) {
  int c = blockIdx.x*256 + threadIdx.x;   // grid 4 x 256
  float s = 0.f, ss = 0.f;
  #pragma unroll 8
  for (int rb = 0; rb < RB4; ++rb) {
    s  += ps4[(size_t)rb*2048 + c];
    ss += ps4[(size_t)rb*2048 + 1024 + c];
  }
  float m = s * (1.f/NN);
  float v = ss * (1.f/NN) - m*m;
  stats[c] = m;
  stats[1024 + c] = rsqrtf(v + 1e-5f);
}

// apply BN+relu to pooled raw max/min [64,1024]
__global__ void k_bnpool(const unsigned* __restrict__ pmax, const unsigned* __restrict__ pmin,
                         const float* __restrict__ stats, const float* __restrict__ g,
                         const float* __restrict__ be, float* __restrict__ p) {
  int i = blockIdx.x*256 + threadIdx.x;
  if (i >= 64*1024) return;
  int c = i & 1023;
  float mean = stats[c], rstd = stats[1024+c];
  float sc = g[c]*rstd, sh = be[c] - mean*sc;
  float v = (sc >= 0.f) ? fdec(pmax[i]) : fdec(pmin[i]);
  p[i] = fmaxf(v*sc + sh, 0.f);
}

// ---------------- FC head: K-split LDS-tiled GEMM + atomics ----------------

template<int K, int OUT, int KT>
__global__ __launch_bounds__(256) void k_fc_tile(
    const float* __restrict__ A, const float* __restrict__ W,
    float* __restrict__ out) {
  __shared__ float As[64][KT];
  __shared__ float Ws[KT][64];
  int t = threadIdx.y*64 + threadIdx.x;
  int j0 = blockIdx.x*64;
  int k0 = blockIdx.y*KT;
  #pragma unroll 4
  for (int i = t; i < 64*KT/4; i += 256) {
    int r  = i / (KT/4);
    int c4 = i % (KT/4);
    float4 v = *(const float4*)&A[r*K + k0 + c4*4];
    *(float4*)&As[r][c4*4] = v;
  }
  #pragma unroll 4
  for (int i = t; i < KT*16; i += 256) {
    int k  = i / 16;
    int c4 = i % 16;
    float4 v = *(const float4*)&W[(k0+k)*OUT + j0 + c4*4];
    *(float4*)&Ws[k][c4*4] = v;
  }
  __syncthreads();
  int j  = threadIdx.x;
  int r0 = threadIdx.y*16;
  float acc[16] = {};
  for (int kk = 0; kk < KT; ++kk) {
    float w = Ws[kk][j];
    #pragma unroll
    for (int i = 0; i < 16; ++i) acc[i] += As[r0+i][kk] * w;
  }
  #pragma unroll
  for (int i = 0; i < 16; ++i) atomicAdd(&out[(r0+i)*OUT + j0 + j], acc[i]);
}

__global__ __launch_bounds__(512) void k_bn_rows(
    float* __restrict__ h, const float* __restrict__ g,
    const float* __restrict__ be, int C) {
  int c = blockIdx.x*64 + threadIdx.x;
  int y = threadIdx.y;
  float v[8];
  float s = 0.f, ss = 0.f;
  #pragma unroll
  for (int i = 0; i < 8; ++i) {
    v[i] = h[(y*8+i)*C + c];
    s += v[i]; ss += v[i]*v[i];
  }
  __shared__ float rs[8][64], rss[8][64], bc[2][64];
  rs[y][threadIdx.x] = s; rss[y][threadIdx.x] = ss;
  __syncthreads();
  if (y == 0) {
    s = 0.f; ss = 0.f;
    #pragma unroll
    for (int i = 0; i < 8; ++i) { s += rs[i][threadIdx.x]; ss += rss[i][threadIdx.x]; }
    float m = s*(1.f/64.f);
    float var = ss*(1.f/64.f) - m*m;
    float rstd = rsqrtf(var + 1e-5f);
    float sc = g[c]*rstd;
    bc[0][threadIdx.x] = sc;
    bc[1][threadIdx.x] = be[c] - m*sc;
  }
  __syncthreads();
  float sc = bc[0][threadIdx.x], sh = bc[1][threadIdx.x];
  #pragma unroll
  for (int i = 0; i < 8; ++i)
    h[(y*8+i)*C + c] = fmaxf(v[i]*sc + sh, 0.f);
}

// add b7 then L2-normalize rows of [64,64]
__global__ void k_l2norm(const float* __restrict__ in, const float* __restrict__ b,
                         float* __restrict__ out) {
  int r = blockIdx.x, j = threadIdx.x;
  float v = in[r*64 + j] + b[j];
  float ss = v*v;
  #pragma unroll
  for (int off = 1; off < 64; off <<= 1) ss += __shfl_xor(ss, off);
  float inv = 1.f / fmaxf(sqrtf(ss), 1e-12f);
  out[r*64 + j] = v * inv;
}

// ---------------- launch ----------------

extern "C" void kernel_launch(void* const* d_in, const int* in_sizes, int n_in,
                              void* d_out, int out_size, void* d_ws, size_t ws_size,
                              hipStream_t stream) {
  const float* x    = (const float*)d_in[0];
  const int*   ei   = (const int*)d_in[1];
  const int*   batch= (const int*)d_in[2];
  const float* W1=(const float*)d_in[3],  *g1=(const float*)d_in[5],  *be1=(const float*)d_in[6];
  const float* W2=(const float*)d_in[7],  *g2=(const float*)d_in[9],  *be2=(const float*)d_in[10];
  const float* W3=(const float*)d_in[11], *g3=(const float*)d_in[13], *be3=(const float*)d_in[14];
  const float* W4=(const float*)d_in[15], *g4=(const float*)d_in[17], *be4=(const float*)d_in[18];
  const float* W5=(const float*)d_in[19], *g5=(const float*)d_in[21], *be5=(const float*)d_in[22];
  const float* W6=(const float*)d_in[23], *g6=(const float*)d_in[25], *be6=(const float*)d_in[26];
  const float* W7=(const float*)d_in[27], *b7=(const float*)d_in[28];
  const int* esrc = ei;
  const int* edst = ei + EE;

  char* w = (char*)d_ws;
  auto alloc = [&](size_t bytes) -> void* {
    void* p = (void*)w;
    w += (bytes + 255) & ~(size_t)255;
    return p;
  };
  int*   deg     = (int*)  alloc(NN*4);
  int*   offsets = (int*)  alloc((NN+1)*4);
  int*   cursor  = (int*)  alloc(NN*4);
  int*   bsum    = (int*)  alloc(32*4);
  float* dinv    = (float*)alloc(NN*4);
  int*   csr_src = (int*)  alloc((EE+NN)*4);
  float* csr_w   = (float*)alloc((EE+NN)*4);
  float* stats1  = (float*)alloc(2*32*4);
  float* stats2  = (float*)alloc(2*64*4);
  float* stats3  = (float*)alloc(2*128*4);
  float* stats4  = (float*)alloc(2*1024*4);
  float* pstats  = (float*)alloc(16*2*128*4);
  float* ps4     = (float*)alloc((size_t)RB4*2048*4);
  float* agg     = (float*)alloc((size_t)NN*128*4);
  float* hbufA   = (float*)alloc((size_t)NN*128*4);
  float* hbufB   = (float*)alloc((size_t)NN*64*4);
  float* pooled  = (float*)alloc(64*1024*4);
  float* fc1     = (float*)alloc(64*512*4);
  float* fc2     = (float*)alloc(64*256*4);
  float* fc3raw  = (float*)alloc(64*64*4);
  unsigned short* agg_bf = (unsigned short*)alloc((size_t)NN*128*2);
  unsigned short* wt_bf  = (unsigned short*)alloc(1024*128*2);
  unsigned* pmax = (unsigned*)alloc(64*1024*4);
  unsigned* pmin = (unsigned*)alloc(64*1024*4);

  // graph prep (multi-block scan)
  k_prep<<<CDIV(NN,256),256,0,stream>>>(deg);
  k_deg<<<CDIV(EE,256),256,0,stream>>>(edst, deg);
  k_scan_bsum<<<20,256,0,stream>>>(deg, bsum);
  k_scan_apply<<<20,256,0,stream>>>(deg, bsum, offsets, cursor, dinv);
  k_fill<<<CDIV(EE+NN,256),256,0,stream>>>(esrc, edst, dinv, cursor, csr_src, csr_w);

  // ---- layer 1: agg(x) -> gemm(+stats) -> finalize ----
  k_agg<6,8,32><<<CDIV(NN,32),dim3(8,32),0,stream>>>(x, offsets, csr_src, csr_w, agg);
  hipMemsetAsync(pstats, 0, 16*2*32*4, stream);
  k_gemm_small<6,32,32><<<NN/32,256,0,stream>>>(agg, W1, hbufA, pstats);
  k_finalize_ps<32><<<1,64,0,stream>>>(pstats, stats1);

  // ---- layer 2 ----
  k_agg_f4<32,32><<<CDIV(NN,32),dim3(8,32),0,stream>>>(hbufA, stats1, g1, be1, offsets, csr_src, csr_w, agg);
  hipMemsetAsync(pstats, 0, 16*2*64*4, stream);
  k_gemm_small<32,64,16><<<NN/16,256,0,stream>>>(agg, W2, hbufB, pstats);
  k_finalize_ps<64><<<1,64,0,stream>>>(pstats, stats2);

  // ---- layer 3 ----
  k_agg_f4<64,16><<<CDIV(NN,16),dim3(16,16),0,stream>>>(hbufB, stats2, g2, be2, offsets, csr_src, csr_w, agg);
  hipMemsetAsync(pstats, 0, 16*2*128*4, stream);
  k_gemm_small<64,128,16><<<NN/16,256,0,stream>>>(agg, W3, hbufA, pstats);
  k_finalize_ps<128><<<2,64,0,stream>>>(pstats, stats3);

  // ---- layer 4: bf16 gather -> MFMA (partial stats, pooled atomics) ----
  k_agg_bf_f4<<<CDIV(NN,8),dim3(32,8),0,stream>>>(hbufA, stats3, g3, be3, offsets, csr_src, csr_w, agg_bf);
  k_wprep<<<CDIV(128*1024,256),256,0,stream>>>(W4, wt_bf);
  hipMemsetAsync(pmax, 0x00, 64*1024*4, stream);
  hipMemsetAsync(pmin, 0xFF, 64*1024*4, stream);
  k_gemm_l4_mfma<<<dim3(RB4,8),256,0,stream>>>(agg_bf, wt_bf, batch, ps4, pmax, pmin);
  k_finalize_l4<<<4,256,0,stream>>>(ps4, stats4);
  k_bnpool<<<CDIV(64*1024,256),256,0,stream>>>(pmax, pmin, stats4, g4, be4, pooled);

  // ---- FC head (b5,b6 cancel in BN; b7 added in l2norm) ----
  hipMemsetAsync(fc1, 0, 64*512*4, stream);
  k_fc_tile<1024,512,128><<<dim3(8,8),dim3(64,4),0,stream>>>(pooled, W5, fc1);
  k_bn_rows<<<8,dim3(64,8),0,stream>>>(fc1, g5, be5, 512);

  hipMemsetAsync(fc2, 0, 64*256*4, stream);
  k_fc_tile<512,256,128><<<dim3(4,4),dim3(64,4),0,stream>>>(fc1, W6, fc2);
  k_bn_rows<<<4,dim3(64,8),0,stream>>>(fc2, g6, be6, 256);

  hipMemsetAsync(fc3raw, 0, 64*64*4, stream);
  k_fc_tile<256,64,64><<<dim3(1,4),dim3(64,4),0,stream>>>(fc2, W7, fc3raw);
  k_l2norm<<<64,64,0,stream>>>(fc3raw, b7, (float*)d_out);
}

// Round 11
// 337.305 us; speedup vs baseline: 1.0597x; 1.0597x over previous
//
#include <hip/hip_runtime.h>
#include <math.h>

#define NN 20000
#define EE 256000
#define GG 64
#define CDIV(a,b) (((a)+(b)-1)/(b))
#define RB4 157   // CDIV(NN,128) row-blocks in layer-4 GEMM

typedef __attribute__((ext_vector_type(8))) short bf16x8;
typedef __attribute__((ext_vector_type(4))) float f32x4;

__device__ __forceinline__ unsigned fkey(float f) {
  unsigned u = __float_as_uint(f);
  return (u & 0x80000000u) ? ~u : (u | 0x80000000u);
}
__device__ __forceinline__ float fdec(unsigned k) {
  unsigned u = (k & 0x80000000u) ? (k ^ 0x80000000u) : ~k;
  return __uint_as_float(u);
}
__device__ __forceinline__ unsigned short rne_bf16(float f) {
  unsigned u = __float_as_uint(f);
  unsigned r = (u + 0x7fffu + ((u >> 16) & 1u)) >> 16;
  return (unsigned short)r;
}

// ---------------- graph preprocessing ----------------

__global__ void k_prep(int* deg) {
  int i = blockIdx.x*blockDim.x + threadIdx.x;
  if (i < NN) deg[i] = 1;   // self-loop
}

__global__ void k_deg(const int* __restrict__ dst, int* deg) {
  int i = blockIdx.x*blockDim.x + threadIdx.x;
  if (i < EE) atomicAdd(&deg[dst[i]], 1);
}

__global__ __launch_bounds__(256) void k_scan_bsum(const int* __restrict__ deg,
                                                   int* __restrict__ bsum) {
  __shared__ int red[256];
  int b = blockIdx.x, t = threadIdx.x;
  int idx = b*1024 + t*4;
  int4 v = make_int4(0,0,0,0);
  if (idx < NN) v = *(const int4*)&deg[idx];
  red[t] = v.x + v.y + v.z + v.w;
  __syncthreads();
  for (int off = 128; off > 0; off >>= 1) {
    if (t < off) red[t] += red[t+off];
    __syncthreads();
  }
  if (t == 0) bsum[b] = red[0];
}

__global__ __launch_bounds__(256) void k_scan_apply(
    const int* __restrict__ deg, const int* __restrict__ bsum,
    int* __restrict__ offsets, int* __restrict__ cursor, float* __restrict__ dinv) {
  __shared__ int base_s;
  __shared__ int tsum[256];
  int b = blockIdx.x, t = threadIdx.x;
  if (t == 0) {
    int s = 0;
    for (int i = 0; i < b; ++i) s += bsum[i];
    base_s = s;
  }
  int idx = b*1024 + t*4;
  int4 v = make_int4(0,0,0,0);
  if (idx < NN) v = *(const int4*)&deg[idx];
  tsum[t] = v.x + v.y + v.z + v.w;
  __syncthreads();
  for (int off = 1; off < 256; off <<= 1) {
    int u = (t >= off) ? tsum[t-off] : 0;
    __syncthreads();
    tsum[t] += u;
    __syncthreads();
  }
  int excl = (t == 0) ? 0 : tsum[t-1];
  if (idx < NN) {
    int base = base_s + excl;
    int o0 = base;
    int o1 = o0 + v.x;
    int o2 = o1 + v.y;
    int o3 = o2 + v.z;
    *(int4*)&offsets[idx] = make_int4(o0,o1,o2,o3);
    *(int4*)&cursor[idx]  = make_int4(o0,o1,o2,o3);
    float4 dv;
    dv.x = rsqrtf((float)v.x); dv.y = rsqrtf((float)v.y);
    dv.z = rsqrtf((float)v.z); dv.w = rsqrtf((float)v.w);
    *(float4*)&dinv[idx] = dv;
    if (idx + 4 == NN) offsets[NN] = o3 + v.w;
  }
}

__global__ void k_fill(const int* __restrict__ srcv, const int* __restrict__ dstv,
                       const float* __restrict__ dinv, int* cursor,
                       int* __restrict__ csr_src, float* __restrict__ csr_w) {
  int i = blockIdx.x*blockDim.x + threadIdx.x;
  if (i < EE) {
    int s = srcv[i], d = dstv[i];
    int pos = atomicAdd(&cursor[d], 1);
    csr_src[pos] = s;
    csr_w[pos] = dinv[s] * dinv[d];
  } else if (i < EE + NN) {
    int n = i - EE;
    int pos = atomicAdd(&cursor[n], 1);
    csr_src[pos] = n;
    float di = dinv[n];
    csr_w[pos] = di * di;
  }
}

// ---------------- aggregation ----------------

template<int C, int TX, int TY>
__global__ void k_agg(const float* __restrict__ in, const int* __restrict__ offsets,
                      const int* __restrict__ csr_src, const float* __restrict__ csr_w,
                      float* __restrict__ out) {
  int node = blockIdx.x * TY + threadIdx.y;
  if (node >= NN) return;
  int x = threadIdx.x;
  int k0 = offsets[node], k1 = offsets[node+1];
  if (x < C) {
    float acc = 0.f;
    for (int k = k0; k < k1; ++k) {
      int s = csr_src[k];
      float w = csr_w[k];
      acc += w * in[s*C + x];
    }
    out[node*C + x] = acc;
  }
}

// layers 2-3: gather + fused BN/ReLU, float4 lanes, 2-way edge unroll for ILP
template<int C, int TY>
__global__ void k_agg_f4(const float* __restrict__ in, const float* __restrict__ st,
                         const float* __restrict__ g, const float* __restrict__ be,
                         const int* __restrict__ offsets, const int* __restrict__ csr_src,
                         const float* __restrict__ csr_w, float* __restrict__ out) {
  int node = blockIdx.x*TY + threadIdx.y;
  if (node >= NN) return;
  int c0 = threadIdx.x*4;
  float4 mean = *(const float4*)&st[c0];
  float4 rstd = *(const float4*)&st[C+c0];
  float4 gv = *(const float4*)&g[c0];
  float4 bv = *(const float4*)&be[c0];
  float sx = gv.x*rstd.x, hx = bv.x - mean.x*sx;
  float sy = gv.y*rstd.y, hy = bv.y - mean.y*sy;
  float sz = gv.z*rstd.z, hz = bv.z - mean.z*sz;
  float sw = gv.w*rstd.w, hw = bv.w - mean.w*sw;
  int k0 = offsets[node], k1 = offsets[node+1];
  float p0=0.f,p1=0.f,p2=0.f,p3=0.f;
  float q0=0.f,q1=0.f,q2=0.f,q3=0.f;
  int k = k0;
  for (; k + 2 <= k1; k += 2) {
    int s0 = csr_src[k], s1 = csr_src[k+1];
    float w0 = csr_w[k], w1 = csr_w[k+1];
    float4 u = *(const float4*)&in[s0*C + c0];
    float4 v = *(const float4*)&in[s1*C + c0];
    p0 += w0*fmaxf(u.x*sx+hx, 0.f);
    p1 += w0*fmaxf(u.y*sy+hy, 0.f);
    p2 += w0*fmaxf(u.z*sz+hz, 0.f);
    p3 += w0*fmaxf(u.w*sw+hw, 0.f);
    q0 += w1*fmaxf(v.x*sx+hx, 0.f);
    q1 += w1*fmaxf(v.y*sy+hy, 0.f);
    q2 += w1*fmaxf(v.z*sz+hz, 0.f);
    q3 += w1*fmaxf(v.w*sw+hw, 0.f);
  }
  if (k < k1) {
    int s0 = csr_src[k]; float w0 = csr_w[k];
    float4 u = *(const float4*)&in[s0*C + c0];
    p0 += w0*fmaxf(u.x*sx+hx, 0.f);
    p1 += w0*fmaxf(u.y*sy+hy, 0.f);
    p2 += w0*fmaxf(u.z*sz+hz, 0.f);
    p3 += w0*fmaxf(u.w*sw+hw, 0.f);
  }
  *(float4*)&out[node*C+c0] = make_float4(p0+q0, p1+q1, p2+q2, p3+q3);
}

// layer-4: gather [N,128] + fused BN/ReLU, emits bf16, 2-way edge unroll
__global__ void k_agg_bf_f4(const float* __restrict__ in, const float* __restrict__ st,
                            const float* __restrict__ g, const float* __restrict__ be,
                            const int* __restrict__ offsets, const int* __restrict__ csr_src,
                            const float* __restrict__ csr_w, unsigned short* __restrict__ out) {
  int node = blockIdx.x*8 + threadIdx.y;   // block (32,8)
  if (node >= NN) return;
  int c0 = threadIdx.x*4;
  float4 mean = *(const float4*)&st[c0];
  float4 rstd = *(const float4*)&st[128+c0];
  float4 gv = *(const float4*)&g[c0];
  float4 bv = *(const float4*)&be[c0];
  float sx = gv.x*rstd.x, hx = bv.x - mean.x*sx;
  float sy = gv.y*rstd.y, hy = bv.y - mean.y*sy;
  float sz = gv.z*rstd.z, hz = bv.z - mean.z*sz;
  float sw = gv.w*rstd.w, hw = bv.w - mean.w*sw;
  int k0 = offsets[node], k1 = offsets[node+1];
  float p0=0.f,p1=0.f,p2=0.f,p3=0.f;
  float q0=0.f,q1=0.f,q2=0.f,q3=0.f;
  int k = k0;
  for (; k + 2 <= k1; k += 2) {
    int s0 = csr_src[k], s1 = csr_src[k+1];
    float w0 = csr_w[k], w1 = csr_w[k+1];
    float4 u = *(const float4*)&in[s0*128 + c0];
    float4 v = *(const float4*)&in[s1*128 + c0];
    p0 += w0*fmaxf(u.x*sx+hx, 0.f);
    p1 += w0*fmaxf(u.y*sy+hy, 0.f);
    p2 += w0*fmaxf(u.z*sz+hz, 0.f);
    p3 += w0*fmaxf(u.w*sw+hw, 0.f);
    q0 += w1*fmaxf(v.x*sx+hx, 0.f);
    q1 += w1*fmaxf(v.y*sy+hy, 0.f);
    q2 += w1*fmaxf(v.z*sz+hz, 0.f);
    q3 += w1*fmaxf(v.w*sw+hw, 0.f);
  }
  if (k < k1) {
    int s0 = csr_src[k]; float w0 = csr_w[k];
    float4 u = *(const float4*)&in[s0*128 + c0];
    p0 += w0*fmaxf(u.x*sx+hx, 0.f);
    p1 += w0*fmaxf(u.y*sy+hy, 0.f);
    p2 += w0*fmaxf(u.z*sz+hz, 0.f);
    p3 += w0*fmaxf(u.w*sw+hw, 0.f);
  }
  ushort4 o;
  o.x = rne_bf16(p0+q0); o.y = rne_bf16(p1+q1);
  o.z = rne_bf16(p2+q2); o.w = rne_bf16(p3+q3);
  *(ushort4*)&out[node*128 + c0] = o;
}

// W4 [128,1024] fp32 -> Wt [1024,128] bf16
__global__ void k_wprep(const float* __restrict__ W, unsigned short* __restrict__ out) {
  int i = blockIdx.x*256 + threadIdx.x;
  if (i >= 128*1024) return;
  int k = i >> 10, c = i & 1023;
  out[c*128 + k] = rne_bf16(W[i]);
}

// ---------------- small GEMM (layers 1-3), no bias, fused stats ----------------

template<int K, int OUT, int ROWS>
__global__ __launch_bounds__(256) void k_gemm_small(
    const float* __restrict__ A, const float* __restrict__ W,
    float* __restrict__ out, float* __restrict__ pstats) {
  constexpr int RG  = 256 / OUT;
  constexpr int RPT = ROWS / RG;
  __shared__ float Ws[K*OUT];
  __shared__ float As[ROWS*K];
  __shared__ float reds[2][RG][OUT];
  int t = threadIdx.x;
  for (int i = t; i < K*OUT; i += 256) Ws[i] = W[i];
  int row0 = blockIdx.x * ROWS;
  for (int i = t; i < ROWS*K; i += 256) As[i] = A[row0*K + i];
  __syncthreads();
  int j  = t % OUT;
  int rg = t / OUT;
  float acc[RPT] = {};
  for (int k = 0; k < K; ++k) {
    float w = Ws[k*OUT + j];
    #pragma unroll
    for (int i = 0; i < RPT; ++i)
      acc[i] += As[(rg*RPT + i)*K + k] * w;
  }
  float s = 0.f, ss = 0.f;
  #pragma unroll
  for (int i = 0; i < RPT; ++i) {
    out[(row0 + rg*RPT + i)*OUT + j] = acc[i];
    s += acc[i]; ss += acc[i]*acc[i];
  }
  reds[0][rg][j] = s; reds[1][rg][j] = ss;
  __syncthreads();
  if (rg == 0) {
    float S = 0.f, SS = 0.f;
    #pragma unroll
    for (int r = 0; r < RG; ++r) { S += reds[0][r][j]; SS += reds[1][r][j]; }
    int p = blockIdx.x & 15;
    atomicAdd(&pstats[p*2*OUT + j], S);
    atomicAdd(&pstats[p*2*OUT + OUT + j], SS);
  }
}

template<int C>
__global__ void k_finalize_ps(const float* __restrict__ pstats, float* __restrict__ stats) {
  int c = blockIdx.x*64 + threadIdx.x;
  if (c >= C) return;
  float s = 0.f, ss = 0.f;
  #pragma unroll
  for (int p = 0; p < 16; ++p) { s += pstats[p*2*C + c]; ss += pstats[p*2*C + C + c]; }
  float m = s * (1.f/NN);
  float v = ss * (1.f/NN) - m*m;
  stats[c] = m;
  stats[C+c] = rsqrtf(v + 1e-5f);
}

// ---------------- layer-4: bf16 MFMA GEMM, A staged once, 2 col-panels per block ----------------

__global__ __launch_bounds__(256) void k_gemm_l4_mfma(
    const unsigned short* __restrict__ A, const unsigned short* __restrict__ Bt,
    const int* __restrict__ batch,
    float* __restrict__ ps4, unsigned* __restrict__ pmax, unsigned* __restrict__ pmin) {
  __shared__ unsigned short As[128*128];
  __shared__ unsigned short Bs[128*128];
  __shared__ float scr_s[512];
  __shared__ float scr_p[512];
  int t = threadIdx.x;
  int row0 = blockIdx.x * 128;
  // stage A once for both panels
  #pragma unroll
  for (int j = 0; j < 8; ++j) {
    int c = j*256 + t;
    int r = c >> 4, ck = c & 15;
    int rg = row0 + r;
    ulonglong2 v; v.x = 0; v.y = 0;
    if (rg < NN) v = *(const ulonglong2*)&A[(size_t)rg*128 + ck*8];
    *(ulonglong2*)&As[r*128 + (ck ^ (r & 7))*8] = v;
  }
  int w = t >> 6, l = t & 63;
  int wr = w >> 1, wc = w & 1;
  int lrow = l & 15, lk = l >> 4;
  int rbase = row0 + wr*64;
  int rlast_b = min(row0 + 127, NN - 1);
  int glo_b = batch[row0], ghi_b = batch[rlast_b];
  bool block_same = (glo_b == ghi_b);

  for (int p = 0; p < 2; ++p) {
    int col0 = (blockIdx.y*2 + p)*128;
    if (p) __syncthreads();   // prior panel's Bs reads + scr reads complete
    #pragma unroll
    for (int j = 0; j < 8; ++j) {
      int c = j*256 + t;
      int r = c >> 4, ck = c & 15;
      ulonglong2 v = *(const ulonglong2*)&Bt[(size_t)(col0 + r)*128 + ck*8];
      *(ulonglong2*)&Bs[r*128 + (ck ^ (r & 7))*8] = v;
    }
    __syncthreads();

    f32x4 acc[4][4] = {};
    #pragma unroll
    for (int ks = 0; ks < 4; ++ks) {
      int kc = ks*4 + lk;
      bf16x8 a[4], b[4];
      #pragma unroll
      for (int m = 0; m < 4; ++m) {
        int r = wr*64 + m*16 + lrow;
        a[m] = *(const bf16x8*)&As[r*128 + (kc ^ (r & 7))*8];
      }
      #pragma unroll
      for (int n = 0; n < 4; ++n) {
        int r = wc*64 + n*16 + lrow;
        b[n] = *(const bf16x8*)&Bs[r*128 + (kc ^ (r & 7))*8];
      }
      #pragma unroll
      for (int m = 0; m < 4; ++m)
        #pragma unroll
        for (int n = 0; n < 4; ++n)
          acc[m][n] = __builtin_amdgcn_mfma_f32_16x16x32_bf16(a[m], b[n], acc[m][n], 0, 0, 0);
    }

    // ---- epilogue for this panel ----
    float s[4] = {}, ss[4] = {};
    float mx[4], mn[4];
    #pragma unroll
    for (int n = 0; n < 4; ++n) { mx[n] = -3.4e38f; mn[n] = 3.4e38f; }
    #pragma unroll
    for (int m = 0; m < 4; ++m)
      #pragma unroll
      for (int r = 0; r < 4; ++r) {
        int row_g = rbase + m*16 + lk*4 + r;
        if (row_g < NN) {
          #pragma unroll
          for (int n = 0; n < 4; ++n) {
            float v = acc[m][n][r];
            s[n] += v; ss[n] += v*v;
            mx[n] = fmaxf(mx[n], v); mn[n] = fminf(mn[n], v);
          }
        }
      }
    #pragma unroll
    for (int n = 0; n < 4; ++n) {
      s[n]  += __shfl_xor(s[n], 16);  s[n]  += __shfl_xor(s[n], 32);
      ss[n] += __shfl_xor(ss[n], 16); ss[n] += __shfl_xor(ss[n], 32);
    }
    if (block_same) {
      #pragma unroll
      for (int n = 0; n < 4; ++n) {
        mx[n] = fmaxf(mx[n], __shfl_xor(mx[n], 16)); mx[n] = fmaxf(mx[n], __shfl_xor(mx[n], 32));
        mn[n] = fminf(mn[n], __shfl_xor(mn[n], 16)); mn[n] = fminf(mn[n], __shfl_xor(mn[n], 32));
      }
    }
    if (l < 16) {
      #pragma unroll
      for (int n = 0; n < 4; ++n) {
        int si = (((wr*2 + wc)*4 + n)*16 + l)*2;
        scr_s[si]   = s[n];
        scr_s[si+1] = ss[n];
        if (block_same) { scr_p[si] = mx[n]; scr_p[si+1] = mn[n]; }
      }
    }
    __syncthreads();
    if (wr == 0 && l < 16) {
      #pragma unroll
      for (int n = 0; n < 4; ++n) {
        int si0 = (((0*2 + wc)*4 + n)*16 + l)*2;
        int si1 = (((1*2 + wc)*4 + n)*16 + l)*2;
        int cg  = col0 + wc*64 + n*16 + l;
        ps4[(size_t)blockIdx.x*2048 + cg]        = scr_s[si0]   + scr_s[si1];
        ps4[(size_t)blockIdx.x*2048 + 1024 + cg] = scr_s[si0+1] + scr_s[si1+1];
        if (block_same) {
          float bmx = fmaxf(scr_p[si0],   scr_p[si1]);
          float bmn = fminf(scr_p[si0+1], scr_p[si1+1]);
          if (bmx > -3.0e38f) atomicMax(&pmax[glo_b*1024 + cg], fkey(bmx));
          if (bmn <  3.0e38f) atomicMin(&pmin[glo_b*1024 + cg], fkey(bmn));
        }
      }
    }
    if (!block_same && rbase < NN) {
      int rlast = min(rbase + 63, NN - 1);
      int glo = batch[rbase], ghi = batch[rlast];
      if (glo == ghi) {
        #pragma unroll
        for (int n = 0; n < 4; ++n) {
          mx[n] = fmaxf(mx[n], __shfl_xor(mx[n], 16)); mx[n] = fmaxf(mx[n], __shfl_xor(mx[n], 32));
          mn[n] = fminf(mn[n], __shfl_xor(mn[n], 16)); mn[n] = fminf(mn[n], __shfl_xor(mn[n], 32));
        }
        if (l < 16) {
          #pragma unroll
          for (int n = 0; n < 4; ++n) {
            int cg = col0 + wc*64 + n*16 + l;
            atomicMax(&pmax[glo*1024 + cg], fkey(mx[n]));
            atomicMin(&pmin[glo*1024 + cg], fkey(mn[n]));
          }
        }
      } else {
        int gb[4][4];
        #pragma unroll
        for (int m = 0; m < 4; ++m)
          #pragma unroll
          for (int r = 0; r < 4; ++r) {
            int row_g = rbase + m*16 + lk*4 + r;
            gb[m][r] = (row_g < NN) ? batch[row_g] : -1;
          }
        for (int g = glo; g <= ghi; ++g) {
          float gmx[4], gmn[4];
          #pragma unroll
          for (int n = 0; n < 4; ++n) { gmx[n] = -3.4e38f; gmn[n] = 3.4e38f; }
          #pragma unroll
          for (int m = 0; m < 4; ++m)
            #pragma unroll
            for (int r = 0; r < 4; ++r) {
              bool in_g = (gb[m][r] == g);
              #pragma unroll
              for (int n = 0; n < 4; ++n) {
                float v = acc[m][n][r];
                gmx[n] = in_g ? fmaxf(gmx[n], v) : gmx[n];
                gmn[n] = in_g ? fminf(gmn[n], v) : gmn[n];
              }
            }
          #pragma unroll
          for (int n = 0; n < 4; ++n) {
            gmx[n] = fmaxf(gmx[n], __shfl_xor(gmx[n], 16)); gmx[n] = fmaxf(gmx[n], __shfl_xor(gmx[n], 32));
            gmn[n] = fminf(gmn[n], __shfl_xor(gmn[n], 16)); gmn[n] = fminf(gmn[n], __shfl_xor(gmn[n], 32));
          }
          if (l < 16) {
            #pragma unroll
            for (int n = 0; n < 4; ++n) {
              int cg = col0 + wc*64 + n*16 + l;
              if (gmx[n] > -3.0e38f) atomicMax(&pmax[g*1024 + cg], fkey(gmx[n]));
              if (gmn[n] <  3.0e38f) atomicMin(&pmin[g*1024 + cg], fkey(gmn[n]));
            }
          }
        }
      }
    }
  }
}

// reduce ps4 [RB4][2][1024] -> stats4 [2][1024]
__global__ void k_finalize_l4(const float* __restrict__ ps4, float* __restrict__ stats) {
  int c = blockIdx.x*256 + threadIdx.x;   // grid 4 x 256
  float s = 0.f, ss = 0.f;
  #pragma unroll 8
  for (int rb = 0; rb < RB4; ++rb) {
    s  += ps4[(size_t)rb*2048 + c];
    ss += ps4[(size_t)rb*2048 + 1024 + c];
  }
  float m = s * (1.f/NN);
  float v = ss * (1.f/NN) - m*m;
  stats[c] = m;
  stats[1024 + c] = rsqrtf(v + 1e-5f);
}

// apply BN+relu to pooled raw max/min [64,1024]
__global__ void k_bnpool(const unsigned* __restrict__ pmax, const unsigned* __restrict__ pmin,
                         const float* __restrict__ stats, const float* __restrict__ g,
                         const float* __restrict__ be, float* __restrict__ p) {
  int i = blockIdx.x*256 + threadIdx.x;
  if (i >= 64*1024) return;
  int c = i & 1023;
  float mean = stats[c], rstd = stats[1024+c];
  float sc = g[c]*rstd, sh = be[c] - mean*sc;
  float v = (sc >= 0.f) ? fdec(pmax[i]) : fdec(pmin[i]);
  p[i] = fmaxf(v*sc + sh, 0.f);
}

// ---------------- FC head: K-split LDS-tiled GEMM + atomics ----------------

template<int K, int OUT, int KT>
__global__ __launch_bounds__(256) void k_fc_tile(
    const float* __restrict__ A, const float* __restrict__ W,
    float* __restrict__ out) {
  __shared__ float As[64][KT];
  __shared__ float Ws[KT][64];
  int t = threadIdx.y*64 + threadIdx.x;
  int j0 = blockIdx.x*64;
  int k0 = blockIdx.y*KT;
  #pragma unroll 4
  for (int i = t; i < 64*KT/4; i += 256) {
    int r  = i / (KT/4);
    int c4 = i % (KT/4);
    float4 v = *(const float4*)&A[r*K + k0 + c4*4];
    *(float4*)&As[r][c4*4] = v;
  }
  #pragma unroll 4
  for (int i = t; i < KT*16; i += 256) {
    int k  = i / 16;
    int c4 = i % 16;
    float4 v = *(const float4*)&W[(k0+k)*OUT + j0 + c4*4];
    *(float4*)&Ws[k][c4*4] = v;
  }
  __syncthreads();
  int j  = threadIdx.x;
  int r0 = threadIdx.y*16;
  float acc[16] = {};
  for (int kk = 0; kk < KT; ++kk) {
    float w = Ws[kk][j];
    #pragma unroll
    for (int i = 0; i < 16; ++i) acc[i] += As[r0+i][kk] * w;
  }
  #pragma unroll
  for (int i = 0; i < 16; ++i) atomicAdd(&out[(r0+i)*OUT + j0 + j], acc[i]);
}

__global__ __launch_bounds__(512) void k_bn_rows(
    float* __restrict__ h, const float* __restrict__ g,
    const float* __restrict__ be, int C) {
  int c = blockIdx.x*64 + threadIdx.x;
  int y = threadIdx.y;
  float v[8];
  float s = 0.f, ss = 0.f;
  #pragma unroll
  for (int i = 0; i < 8; ++i) {
    v[i] = h[(y*8+i)*C + c];
    s += v[i]; ss += v[i]*v[i];
  }
  __shared__ float rs[8][64], rss[8][64], bc[2][64];
  rs[y][threadIdx.x] = s; rss[y][threadIdx.x] = ss;
  __syncthreads();
  if (y == 0) {
    s = 0.f; ss = 0.f;
    #pragma unroll
    for (int i = 0; i < 8; ++i) { s += rs[i][threadIdx.x]; ss += rss[i][threadIdx.x]; }
    float m = s*(1.f/64.f);
    float var = ss*(1.f/64.f) - m*m;
    float rstd = rsqrtf(var + 1e-5f);
    float sc = g[c]*rstd;
    bc[0][threadIdx.x] = sc;
    bc[1][threadIdx.x] = be[c] - m*sc;
  }
  __syncthreads();
  float sc = bc[0][threadIdx.x], sh = bc[1][threadIdx.x];
  #pragma unroll
  for (int i = 0; i < 8; ++i)
    h[(y*8+i)*C + c] = fmaxf(v[i]*sc + sh, 0.f);
}

// add b7 then L2-normalize rows of [64,64]
__global__ void k_l2norm(const float* __restrict__ in, const float* __restrict__ b,
                         float* __restrict__ out) {
  int r = blockIdx.x, j = threadIdx.x;
  float v = in[r*64 + j] + b[j];
  float ss = v*v;
  #pragma unroll
  for (int off = 1; off < 64; off <<= 1) ss += __shfl_xor(ss, off);
  float inv = 1.f / fmaxf(sqrtf(ss), 1e-12f);
  out[r*64 + j] = v * inv;
}

// ---------------- launch ----------------

extern "C" void kernel_launch(void* const* d_in, const int* in_sizes, int n_in,
                              void* d_out, int out_size, void* d_ws, size_t ws_size,
                              hipStream_t stream) {
  const float* x    = (const float*)d_in[0];
  const int*   ei   = (const int*)d_in[1];
  const int*   batch= (const int*)d_in[2];
  const float* W1=(const float*)d_in[3],  *g1=(const float*)d_in[5],  *be1=(const float*)d_in[6];
  const float* W2=(const float*)d_in[7],  *g2=(const float*)d_in[9],  *be2=(const float*)d_in[10];
  const float* W3=(const float*)d_in[11], *g3=(const float*)d_in[13], *be3=(const float*)d_in[14];
  const float* W4=(const float*)d_in[15], *g4=(const float*)d_in[17], *be4=(const float*)d_in[18];
  const float* W5=(const float*)d_in[19], *g5=(const float*)d_in[21], *be5=(const float*)d_in[22];
  const float* W6=(const float*)d_in[23], *g6=(const float*)d_in[25], *be6=(const float*)d_in[26];
  const float* W7=(const float*)d_in[27], *b7=(const float*)d_in[28];
  const int* esrc = ei;
  const int* edst = ei + EE;

  char* w = (char*)d_ws;
  auto alloc = [&](size_t bytes) -> void* {
    void* p = (void*)w;
    w += (bytes + 255) & ~(size_t)255;
    return p;
  };
  int*   deg     = (int*)  alloc(NN*4);
  int*   offsets = (int*)  alloc((NN+1)*4);
  int*   cursor  = (int*)  alloc(NN*4);
  int*   bsum    = (int*)  alloc(32*4);
  float* dinv    = (float*)alloc(NN*4);
  int*   csr_src = (int*)  alloc((EE+NN)*4);
  float* csr_w   = (float*)alloc((EE+NN)*4);
  float* stats1  = (float*)alloc(2*32*4);
  float* stats2  = (float*)alloc(2*64*4);
  float* stats3  = (float*)alloc(2*128*4);
  float* stats4  = (float*)alloc(2*1024*4);
  float* pstats  = (float*)alloc(16*2*128*4);
  float* ps4     = (float*)alloc((size_t)RB4*2048*4);
  float* agg     = (float*)alloc((size_t)NN*128*4);
  float* hbufA   = (float*)alloc((size_t)NN*128*4);
  float* hbufB   = (float*)alloc((size_t)NN*64*4);
  float* pooled  = (float*)alloc(64*1024*4);
  float* fc1     = (float*)alloc(64*512*4);
  float* fc2     = (float*)alloc(64*256*4);
  float* fc3raw  = (float*)alloc(64*64*4);
  unsigned short* agg_bf = (unsigned short*)alloc((size_t)NN*128*2);
  unsigned short* wt_bf  = (unsigned short*)alloc(1024*128*2);
  unsigned* pmax = (unsigned*)alloc(64*1024*4);
  unsigned* pmin = (unsigned*)alloc(64*1024*4);

  // graph prep (multi-block scan)
  k_prep<<<CDIV(NN,256),256,0,stream>>>(deg);
  k_deg<<<CDIV(EE,256),256,0,stream>>>(edst, deg);
  k_scan_bsum<<<20,256,0,stream>>>(deg, bsum);
  k_scan_apply<<<20,256,0,stream>>>(deg, bsum, offsets, cursor, dinv);
  k_fill<<<CDIV(EE+NN,256),256,0,stream>>>(esrc, edst, dinv, cursor, csr_src, csr_w);

  // ---- layer 1: agg(x) -> gemm(+stats) -> finalize ----
  k_agg<6,8,32><<<CDIV(NN,32),dim3(8,32),0,stream>>>(x, offsets, csr_src, csr_w, agg);
  hipMemsetAsync(pstats, 0, 16*2*32*4, stream);
  k_gemm_small<6,32,32><<<NN/32,256,0,stream>>>(agg, W1, hbufA, pstats);
  k_finalize_ps<32><<<1,64,0,stream>>>(pstats, stats1);

  // ---- layer 2 ----
  k_agg_f4<32,32><<<CDIV(NN,32),dim3(8,32),0,stream>>>(hbufA, stats1, g1, be1, offsets, csr_src, csr_w, agg);
  hipMemsetAsync(pstats, 0, 16*2*64*4, stream);
  k_gemm_small<32,64,16><<<NN/16,256,0,stream>>>(agg, W2, hbufB, pstats);
  k_finalize_ps<64><<<1,64,0,stream>>>(pstats, stats2);

  // ---- layer 3 ----
  k_agg_f4<64,16><<<CDIV(NN,16),dim3(16,16),0,stream>>>(hbufB, stats2, g2, be2, offsets, csr_src, csr_w, agg);
  hipMemsetAsync(pstats, 0, 16*2*128*4, stream);
  k_gemm_small<64,128,16><<<NN/16,256,0,stream>>>(agg, W3, hbufA, pstats);
  k_finalize_ps<128><<<2,64,0,stream>>>(pstats, stats3);

  // ---- layer 4: bf16 gather -> MFMA (A staged once, 2 panels/block) ----
  k_agg_bf_f4<<<CDIV(NN,8),dim3(32,8),0,stream>>>(hbufA, stats3, g3, be3, offsets, csr_src, csr_w, agg_bf);
  k_wprep<<<CDIV(128*1024,256),256,0,stream>>>(W4, wt_bf);
  hipMemsetAsync(pmax, 0x00, 64*1024*4, stream);
  hipMemsetAsync(pmin, 0xFF, 64*1024*4, stream);
  k_gemm_l4_mfma<<<dim3(RB4,4),256,0,stream>>>(agg_bf, wt_bf, batch, ps4, pmax, pmin);
  k_finalize_l4<<<4,256,0,stream>>>(ps4, stats4);
  k_bnpool<<<CDIV(64*1024,256),256,0,stream>>>(pmax, pmin, stats4, g4, be4, pooled);

  // ---- FC head (b5,b6 cancel in BN; b7 added in l2norm) ----
  hipMemsetAsync(fc1, 0, 64*512*4, stream);
  k_fc_tile<1024,512,128><<<dim3(8,8),dim3(64,4),0,stream>>>(pooled, W5, fc1);
  k_bn_rows<<<8,dim3(64,8),0,stream>>>(fc1, g5, be5, 512);

  hipMemsetAsync(fc2, 0, 64*256*4, stream);
  k_fc_tile<512,256,128><<<dim3(4,4),dim3(64,4),0,stream>>>(fc1, W6, fc2);
  k_bn_rows<<<4,dim3(64,8),0,stream>>>(fc2, g6, be6, 256);

  hipMemsetAsync(fc3raw, 0, 64*64*4, stream);
  k_fc_tile<256,64,64><<<dim3(1,4),dim3(64,4),0,stream>>>(fc2, W7, fc3raw);
  k_l2norm<<<64,64,0,stream>>>(fc3raw, b7, (float*)d_out);
}